// Round 2
// baseline (255.412 us; speedup 1.0000x reference)
//
#include <hip/hip_runtime.h>
#include <hip/hip_cooperative_groups.h>
#include <math.h>

namespace cg = cooperative_groups;

#define BB 64
#define II 512
#define HH 2048
#define RR 64

// d_out float offsets
#define OUT_HNEW 0
#define OUT_U    131072
#define OUT_EM   8519680
#define OUT_EV   8552448
#define OUT_AT   8585216
#define OUT_SUR  8585280

// ws float offsets
#define WS_XMAG   0
#define WS_EVMEAN 64
#define WS_ERRSQ  128
#define WS_COEF_A 192
#define WS_COEF_B 256
#define WS_SUR    320
#define WS_CU     384
#define WS_CT     448
#define WS_CH     512
#define WS_FRO2   576
#define WS_EVEC   640
#define WS_PRED   (WS_EVEC + BB*RR)      // 4736
#define WS_ERR    (WS_PRED + BB*II)      // 37504
#define WS_XN     (WS_ERR + BB*II)       // 70272

__device__ __forceinline__ float wave_reduce_sum(float v) {
    #pragma unroll
    for (int o = 32; o > 0; o >>= 1) v += __shfl_down(v, o, 64);
    return v;
}

// x_pred partial dot: pred[b,i] += sum_k h[b,k]*C[i,k] over one k-chunk
__global__ __launch_bounds__(256) void k_pred(const float* __restrict__ h,
                                              const float* __restrict__ C,
                                              float* __restrict__ pred) {
    int it = blockIdx.x & 63;      // i-tile (8 i's)
    int kc = blockIdx.x >> 6;      // k-chunk 0..3 (512 each)
    int b  = threadIdx.x & 63;
    int ig = threadIdx.x >> 6;     // 0..3
    int i0 = it * 8 + ig * 2;
    int k0 = kc * 512;
    const float4* hp = (const float4*)(h + b * HH + k0);
    const float4* c0 = (const float4*)(C + i0 * HH + k0);
    const float4* c1 = (const float4*)(C + (i0 + 1) * HH + k0);
    float a0 = 0.f, a1 = 0.f;
    #pragma unroll 4
    for (int t = 0; t < 128; ++t) {
        float4 hv = hp[t];
        float4 u  = c0[t];
        float4 w  = c1[t];
        a0 += hv.x*u.x + hv.y*u.y + hv.z*u.z + hv.w*u.w;
        a1 += hv.x*w.x + hv.y*w.y + hv.z*w.z + hv.w*w.w;
    }
    atomicAdd(&pred[b * II + i0],     a0);
    atomicAdd(&pred[b * II + i0 + 1], a1);
}

// Per-batch-row: x_mag, error, x_norm, em_new, ev_new, errsq, ev_mean, eV
__global__ __launch_bounds__(256) void k_combine(const float* __restrict__ x,
    const float* __restrict__ error_mean, const float* __restrict__ error_var,
    const float* __restrict__ V, float* __restrict__ ws, float* __restrict__ out)
{
    __shared__ float red[9];
    __shared__ float err_lds[II];
    __shared__ float pr[4][RR];
    int b = blockIdx.x, t = threadIdx.x;
    int lane = t & 63, wid = t >> 6;
    const float* xr  = x + b * II;
    const float* emr = error_mean + b * II;
    const float* evr = error_var + b * II;
    float x1 = xr[t], x2 = xr[t + 256];
    float ev1 = evr[t], ev2 = evr[t + 256];
    float sx  = wave_reduce_sum(x1 * x1 + x2 * x2);
    float sev = wave_reduce_sum(ev1 + ev2);
    if (lane == 0) { red[wid] = sx; red[4 + wid] = sev; }
    __syncthreads();
    if (t == 0) {
        float xm = sqrtf(red[0] + red[1] + red[2] + red[3]);
        ws[WS_XMAG + b] = xm;
        ws[WS_EVMEAN + b] = (red[4] + red[5] + red[6] + red[7]) * (1.0f / II);
        red[8] = xm;
    }
    __syncthreads();
    float xmag = red[8];
    float inv = 1.0f / (xmag + 1e-6f);
    float* err_ws = ws + WS_ERR + b * II;
    float* xn_ws  = ws + WS_XN + b * II;
    float* em_out = out + OUT_EM + b * II;
    float* ev_out = out + OUT_EV + b * II;
    const float* pred = ws + WS_PRED + b * II;
    float serr = 0.f;
    #pragma unroll
    for (int s = 0; s < 2; ++s) {
        int i = t + s * 256;
        float xv  = (s == 0) ? x1 : x2;
        float evv = (s == 0) ? ev1 : ev2;
        float err = xv - tanhf(pred[i]) * xmag;
        err_lds[i] = err;
        err_ws[i]  = err;
        float xn = xv * inv;
        xn = fminf(fmaxf(xn, -1.f), 1.f);
        xn_ws[i] = xn;
        float em_new = 0.95f * emr[i] + 0.05f * err;
        em_out[i] = em_new;
        float d = err - em_new;
        ev_out[i] = 0.95f * evv + 0.05f * d * d;
        serr += err * err;
    }
    serr = wave_reduce_sum(serr);
    if (lane == 0) red[wid] = serr;
    __syncthreads();            // also publishes err_lds
    if (t == 0) ws[WS_ERRSQ + b] = red[0] + red[1] + red[2] + red[3];
    // eV[b,r] = sum_i err[i] * V[i,r]
    int r = t & 63, kg = t >> 6;
    float p = 0.f;
    const float* Vp = V + r;
    int base = kg * 128;
    #pragma unroll 4
    for (int j = 0; j < 128; ++j) p += err_lds[base + j] * Vp[(base + j) * RR];
    pr[kg][r] = p;
    __syncthreads();
    if (kg == 0) ws[WS_EVEC + b * RR + r] = pr[0][r] + pr[1][r] + pr[2][r] + pr[3][r];
}

// Per-batch scalars
__global__ void k_scalars(const float* __restrict__ adaptive_tau,
                          const float* __restrict__ eta_p,
                          const float* __restrict__ tau_sys_p,
                          const float* __restrict__ lls_p,
                          float* __restrict__ ws, float* __restrict__ out)
{
    int b = threadIdx.x;
    if (b >= BB) return;
    float xm  = ws[WS_XMAG + b];
    float rel = sqrtf(ws[WS_ERRSQ + b]) / (xm + 1e-6f);
    float ent = 0.5f * logf(17.07946844534713f * (ws[WS_EVMEAN + b] + 1e-6f));
    ent = fminf(fmaxf(ent, 0.f), 2.f);
    float nat = fminf(0.999f * adaptive_tau[b] + 0.001f * rel, 0.8f);
    out[OUT_AT + b] = nat;
    float ctau = 0.5f * (1.f + 0.1f * ent);
    float etau = 0.3f * ctau + 0.7f * nat;
    float s = 1.f / (1.f + expf(-(rel - etau) * 10.f));
    out[OUT_SUR + b] = s;
    ws[WS_SUR + b] = s;
    float tsys = tau_sys_p[0];
    float tsc  = fmaxf(tsys, 0.01f);
    float tdyn = tsc / (1.f + s * expf(lls_p[0]));
    float teff = fminf(fmaxf(tdyn, 0.01f), 50.f);
    float dt   = fminf(fmaxf(0.1f / (teff + 0.1f), 0.01f), 0.5f);
    float u = 1.f / (1.f + expf(-(tsys - 0.01f) * 100.f));
    ws[WS_COEF_A + b] = u * (1.f - dt) + (1.f - u) * 0.05f;   // h coeff
    ws[WS_COEF_B + b] = u * dt + (1.f - u) * 0.95f;           // h_target coeff
    float lam = 0.01f * (1.f + s);
    ws[WS_CU + b] = 1.f - 0.1f * lam;
    ws[WS_CT + b] = 0.1f * lam;
    ws[WS_CH + b] = 0.1f * eta_p[0] * s;
}

// h_new
__global__ __launch_bounds__(256) void k_hnew(const float* __restrict__ h,
    const float* __restrict__ W, const float* __restrict__ Bm,
    const float* __restrict__ ws, float* __restrict__ out)
{
    int b = threadIdx.x & 63, ig = threadIdx.x >> 6;
    int hh = blockIdx.x * 8 + ig * 2;
    const float4* ep = (const float4*)(ws + WS_ERR + b * II);
    const float4* xp = (const float4*)(ws + WS_XN + b * II);
    const float4* w0 = (const float4*)(W + hh * II);
    const float4* w1 = (const float4*)(W + (hh + 1) * II);
    const float4* m0 = (const float4*)(Bm + hh * II);
    const float4* m1 = (const float4*)(Bm + (hh + 1) * II);
    float aw0 = 0, aw1 = 0, ab0 = 0, ab1 = 0;
    #pragma unroll 4
    for (int t = 0; t < 128; ++t) {
        float4 e = ep[t], xn = xp[t];
        float4 v0 = w0[t], v1 = w1[t], u0 = m0[t], u1 = m1[t];
        aw0 += e.x*v0.x + e.y*v0.y + e.z*v0.z + e.w*v0.w;
        aw1 += e.x*v1.x + e.y*v1.y + e.z*v1.z + e.w*v1.w;
        ab0 += xn.x*u0.x + xn.y*u0.y + xn.z*u0.z + xn.w*u0.w;
        ab1 += xn.x*u1.x + xn.y*u1.y + xn.z*u1.z + xn.w*u1.w;
    }
    float s = ws[WS_SUR + b];
    float A = ws[WS_COEF_A + b], Bc = ws[WS_COEF_B + b];
    float h0 = h[b * HH + hh], h1 = h[b * HH + hh + 1];
    float ht0 = tanhf(0.7f * h0 + 0.2f * ab0 + 0.3f * s * aw0);
    float ht1 = tanhf(0.7f * h1 + 0.2f * ab1 + 0.3f * s * aw1);
    out[OUT_HNEW + b * HH + hh]     = A * h0 + Bc * ht0;
    out[OUT_HNEW + b * HH + hh + 1] = A * h1 + Bc * ht1;
}

// Fused U update: unscaled U_new held in REGISTERS across a grid sync,
// then rescaled and stored once. 1024 blocks x 256 threads x 8 float4
// = 8.39M float4 = exactly U. __launch_bounds__(256,4) -> VGPR<=128 ->
// 4 blocks/CU -> all 1024 blocks co-resident (cooperative requirement).
__global__ __launch_bounds__(256, 4) void k_ufused(
    const float* __restrict__ U, const float* __restrict__ Ut,
    const float* __restrict__ h, float* __restrict__ ws,
    float* __restrict__ uout)
{
    __shared__ float red[4];
    cg::grid_group grid = cg::this_grid();
    int b  = blockIdx.x >> 4;                  // 16 blocks per batch
    int j0 = blockIdx.x * 2048 + threadIdx.x;  // float4 index, stride 256, 8 steps
    int e0 = (j0 << 2) & (131072 - 1);
    int r  = e0 & 63;                          // constant across k (step 1024)
    const float4 ev4 = *(const float4*)(ws + WS_EVEC + b * RR + r);
    float a  = ws[WS_CU + b];
    float tc = ws[WS_CT + b];
    float ch = ws[WS_CH + b];
    const float* hb = h + b * HH;
    float4 un[8];
    float p = 0.f;
    #pragma unroll
    for (int k = 0; k < 8; ++k) {
        int j = j0 + k * 256;
        int e = (j << 2) & (131072 - 1);
        float c = ch * hb[e >> 6];
        float4 u4 = ((const float4*)U)[j];
        float4 t4 = ((const float4*)Ut)[j];
        un[k].x = a * u4.x + tc * t4.x + c * ev4.x;
        un[k].y = a * u4.y + tc * t4.y + c * ev4.y;
        un[k].z = a * u4.z + tc * t4.z + c * ev4.z;
        un[k].w = a * u4.w + tc * t4.w + c * ev4.w;
        p += un[k].x*un[k].x + un[k].y*un[k].y + un[k].z*un[k].z + un[k].w*un[k].w;
    }
    p = wave_reduce_sum(p);
    int lane = threadIdx.x & 63, wid = threadIdx.x >> 6;
    if (lane == 0) red[wid] = p;
    __syncthreads();
    if (threadIdx.x == 0) {
        atomicAdd(&ws[WS_FRO2 + b], red[0] + red[1] + red[2] + red[3]);
        __threadfence();
    }
    grid.sync();
    float f = __hip_atomic_load(&ws[WS_FRO2 + b], __ATOMIC_RELAXED,
                                __HIP_MEMORY_SCOPE_AGENT);
    float s = fminf(1.0f / (sqrtf(f) + 1e-6f), 1.5f);
    #pragma unroll
    for (int k = 0; k < 8; ++k) {
        float4 v;
        v.x = un[k].x * s; v.y = un[k].y * s;
        v.z = un[k].z * s; v.w = un[k].w * s;
        ((float4*)uout)[j0 + k * 256] = v;
    }
}

extern "C" void kernel_launch(void* const* d_in, const int* in_sizes, int n_in,
                              void* d_out, int out_size, void* d_ws, size_t ws_size,
                              hipStream_t stream) {
    const float* x   = (const float*)d_in[0];
    const float* h   = (const float*)d_in[1];
    const float* U   = (const float*)d_in[2];
    const float* Ut  = (const float*)d_in[3];
    const float* em  = (const float*)d_in[4];
    const float* ev  = (const float*)d_in[5];
    const float* at  = (const float*)d_in[6];
    const float* C   = (const float*)d_in[7];
    const float* W   = (const float*)d_in[8];
    const float* Bm  = (const float*)d_in[9];
    const float* V   = (const float*)d_in[10];
    const float* eta = (const float*)d_in[11];
    const float* tau = (const float*)d_in[12];
    const float* lls = (const float*)d_in[13];
    float* out = (float*)d_out;
    float* ws  = (float*)d_ws;
    float* uout = out + OUT_U;

    hipMemsetAsync(ws + WS_PRED, 0, BB * II * sizeof(float), stream);
    hipMemsetAsync(ws + WS_FRO2, 0, BB * sizeof(float), stream);

    k_pred   <<<256, 256, 0, stream>>>(h, C, ws + WS_PRED);
    k_combine<<<64,  256, 0, stream>>>(x, em, ev, V, ws, out);
    k_scalars<<<1,   64,  0, stream>>>(at, eta, tau, lls, ws, out);
    k_hnew   <<<256, 256, 0, stream>>>(h, W, Bm, ws, out);

    void* args[] = {(void*)&U, (void*)&Ut, (void*)&h, (void*)&ws, (void*)&uout};
    hipLaunchCooperativeKernel((void*)k_ufused, dim3(1024), dim3(256),
                               args, 0, stream);
}

// Round 6
// 132.033 us; speedup vs baseline: 1.9345x; 1.9345x over previous
//
#include <hip/hip_runtime.h>
#include <math.h>

#define BB 64
#define II 512
#define HH 2048
#define RR 64

// d_out float offsets
#define OUT_HNEW 0
#define OUT_U    131072
#define OUT_EM   8519680
#define OUT_EV   8552448
#define OUT_AT   8585216
#define OUT_SUR  8585280

// ws float offsets
#define WS_XMAG   0
#define WS_EVMEAN 64
#define WS_ERRSQ  128
#define WS_SUR    192
#define WS_COEF_A 256
#define WS_COEF_B 320
#define WS_CUS    384
#define WS_CTS    448
#define WS_CHS    512
#define WS_EVEC   576                    // 64*64 -> 4672
#define WS_SU     4672
#define WS_ST     4736
#define WS_SUT    4800
#define WS_SH2    4864
#define WS_G      4928                   // 4096 -> 9024
#define WS_GT     9024                   // 4096 -> 13120
#define WS_PRED   13120                  // 32768 -> 45888
#define WS_ERRT   45888                  // [i4][b] float4 -> 78656
#define WS_XNT    78656                  // -> 111424
#define WS_HT     111424                 // [k4][b] float4 -> 242496

__device__ __forceinline__ float wave_reduce_sum(float v) {
    #pragma unroll
    for (int o = 32; o > 0; o >>= 1) v += __shfl_down(v, o, 64);
    return v;
}
__device__ __forceinline__ float dot4(float4 a, float4 b) {
    return a.x*b.x + a.y*b.y + a.z*b.z + a.w*b.w;
}

// h[64][2048] -> hT4[k4][b] (float4 of 4 consecutive k per b)
__global__ __launch_bounds__(256) void k_ht(const float* __restrict__ h,
                                            float* __restrict__ ws) {
    int b = blockIdx.x, t = threadIdx.x;
    const float4* hb4 = (const float4*)(h + b * HH);
    float4* hT4 = (float4*)(ws + WS_HT);
    #pragma unroll
    for (int it = 0; it < 2; ++it) {
        int k4 = t + it * 256;
        hT4[k4 * 64 + b] = hb4[k4];
    }
}

// One read pass over U, Ut: Su, St, Sut, Sh2, g[b,r]=sum_h U*h, gt[b,r]
__global__ __launch_bounds__(256) void k_fro(const float* __restrict__ U,
    const float* __restrict__ Ut, const float* __restrict__ h,
    float* __restrict__ ws)
{
    __shared__ float lds[1024];          // [lh][rg][4]
    int bid = blockIdx.x;
    int b = bid >> 3, sub = bid & 7;
    int t = threadIdx.x;
    int rg = t & 15, lh = t >> 4;
    const float4* U4 = (const float4*)U + (size_t)b * 32768 + (sub * 256 + lh) * 16 + rg;
    const float4* T4 = (const float4*)Ut + (size_t)b * 32768 + (sub * 256 + lh) * 16 + rg;
    const float*  hb = h + b * HH + sub * 256 + lh;
    float su = 0.f, st = 0.f, sut = 0.f, sh2 = 0.f;
    float4 g  = {0,0,0,0};
    float4 gt = {0,0,0,0};
    #pragma unroll 4
    for (int s = 0; s < 16; ++s) {
        float4 u  = U4[s * 256];
        float4 tt = T4[s * 256];
        float hv  = hb[s * 16];
        su  += dot4(u, u);
        st  += dot4(tt, tt);
        sut += dot4(u, tt);
        g.x += hv * u.x;  g.y += hv * u.y;  g.z += hv * u.z;  g.w += hv * u.w;
        gt.x += hv * tt.x; gt.y += hv * tt.y; gt.z += hv * tt.z; gt.w += hv * tt.w;
        if (rg == 0) sh2 += hv * hv;
    }
    // scalar sums: wave reduce, lane0 atomics
    su  = wave_reduce_sum(su);
    st  = wave_reduce_sum(st);
    sut = wave_reduce_sum(sut);
    sh2 = wave_reduce_sum(sh2);
    if ((t & 63) == 0) {
        atomicAdd(&ws[WS_SU + b], su);
        atomicAdd(&ws[WS_ST + b], st);
        atomicAdd(&ws[WS_SUT + b], sut);
        atomicAdd(&ws[WS_SH2 + b], sh2);
    }
    // g reduce over lh (16) per (rg, comp)
    lds[t * 4 + 0] = g.x; lds[t * 4 + 1] = g.y;
    lds[t * 4 + 2] = g.z; lds[t * 4 + 3] = g.w;
    __syncthreads();
    if (t < 64) {
        float v = 0.f;
        #pragma unroll
        for (int l = 0; l < 16; ++l) v += lds[l * 64 + t];
        atomicAdd(&ws[WS_G + b * 64 + t], v);
    }
    __syncthreads();
    lds[t * 4 + 0] = gt.x; lds[t * 4 + 1] = gt.y;
    lds[t * 4 + 2] = gt.z; lds[t * 4 + 3] = gt.w;
    __syncthreads();
    if (t < 64) {
        float v = 0.f;
        #pragma unroll
        for (int l = 0; l < 16; ++l) v += lds[l * 64 + t];
        atomicAdd(&ws[WS_GT + b * 64 + t], v);
    }
}

// x_pred partial dot via transposed h (coalesced)
__global__ __launch_bounds__(256) void k_pred(const float* __restrict__ ws_ht,
                                              const float* __restrict__ C,
                                              float* __restrict__ pred) {
    int it = blockIdx.x & 63;
    int kc = blockIdx.x >> 6;
    int b  = threadIdx.x & 63;
    int ig = threadIdx.x >> 6;
    int i0 = it * 8 + ig * 2;
    const float4* hT4 = (const float4*)ws_ht;       // [k4*64 + b]
    const float4* c0 = (const float4*)(C + i0 * HH);
    const float4* c1 = c0 + 512;
    float a0 = 0.f, a1 = 0.f;
    #pragma unroll 4
    for (int kk = 0; kk < 128; ++kk) {
        int k4 = kc * 128 + kk;
        float4 hv = hT4[k4 * 64 + b];
        float4 u  = c0[k4];
        float4 w  = c1[k4];
        a0 += dot4(hv, u);
        a1 += dot4(hv, w);
    }
    atomicAdd(&pred[b * II + i0],     a0);
    atomicAdd(&pred[b * II + i0 + 1], a1);
}

// Per-batch-row combine: 64 blocks x 128 threads (1 float4 per thread)
__global__ __launch_bounds__(128) void k_combine(const float* __restrict__ x,
    const float* __restrict__ error_mean, const float* __restrict__ error_var,
    const float* __restrict__ V, float* __restrict__ ws, float* __restrict__ out)
{
    __shared__ float red[6];
    __shared__ float err_lds[II];
    __shared__ float pr[2][RR];
    __shared__ float xm_s;
    int b = blockIdx.x, t = threadIdx.x;
    int lane = t & 63, wid = t >> 6;                 // 2 waves
    const float4* xr  = (const float4*)(x + b * II);
    const float4* emr = (const float4*)(error_mean + b * II);
    const float4* evr = (const float4*)(error_var + b * II);
    const float4* pd  = (const float4*)(ws + WS_PRED + b * II);
    float4 x4 = xr[t], em4 = emr[t], ev4 = evr[t], p4 = pd[t];
    float sx  = wave_reduce_sum(dot4(x4, x4));
    float sev = wave_reduce_sum(ev4.x + ev4.y + ev4.z + ev4.w);
    if (lane == 0) { red[wid] = sx; red[2 + wid] = sev; }
    __syncthreads();
    if (t == 0) {
        float xm = sqrtf(red[0] + red[1]);
        ws[WS_XMAG + b] = xm;
        ws[WS_EVMEAN + b] = (red[2] + red[3]) * (1.0f / II);
        xm_s = xm;
    }
    __syncthreads();
    float xmag = xm_s;
    float inv = 1.0f / (xmag + 1e-6f);
    float4 err;
    err.x = x4.x - tanhf(p4.x) * xmag;
    err.y = x4.y - tanhf(p4.y) * xmag;
    err.z = x4.z - tanhf(p4.z) * xmag;
    err.w = x4.w - tanhf(p4.w) * xmag;
    ((float4*)(ws + WS_ERRT))[t * 64 + b] = err;
    err_lds[4*t+0] = err.x; err_lds[4*t+1] = err.y;
    err_lds[4*t+2] = err.z; err_lds[4*t+3] = err.w;
    float4 xn;
    xn.x = fminf(fmaxf(x4.x * inv, -1.f), 1.f);
    xn.y = fminf(fmaxf(x4.y * inv, -1.f), 1.f);
    xn.z = fminf(fmaxf(x4.z * inv, -1.f), 1.f);
    xn.w = fminf(fmaxf(x4.w * inv, -1.f), 1.f);
    ((float4*)(ws + WS_XNT))[t * 64 + b] = xn;
    float4 emn;
    emn.x = 0.95f * em4.x + 0.05f * err.x;
    emn.y = 0.95f * em4.y + 0.05f * err.y;
    emn.z = 0.95f * em4.z + 0.05f * err.z;
    emn.w = 0.95f * em4.w + 0.05f * err.w;
    ((float4*)(out + OUT_EM + b * II))[t] = emn;
    float4 evn;
    float dx = err.x - emn.x, dy = err.y - emn.y, dz = err.z - emn.z, dw = err.w - emn.w;
    evn.x = 0.95f * ev4.x + 0.05f * dx * dx;
    evn.y = 0.95f * ev4.y + 0.05f * dy * dy;
    evn.z = 0.95f * ev4.z + 0.05f * dz * dz;
    evn.w = 0.95f * ev4.w + 0.05f * dw * dw;
    ((float4*)(out + OUT_EV + b * II))[t] = evn;
    float serr = wave_reduce_sum(dot4(err, err));
    if (lane == 0) red[4 + wid] = serr;
    __syncthreads();          // publishes err_lds too
    if (t == 0) ws[WS_ERRSQ + b] = red[4] + red[5];
    // eV[b,r]
    int r = lane, kg = wid;
    float p = 0.f;
    const float* Vp = V + r;
    int base = kg * 256;
    #pragma unroll 4
    for (int j = 0; j < 256; ++j) p += err_lds[base + j] * Vp[(base + j) * RR];
    pr[kg][r] = p;
    __syncthreads();
    if (kg == 0) ws[WS_EVEC + b * RR + r] = pr[0][r] + pr[1][r];
}

// Per-batch scalars + Gram-expanded Frobenius norm -> scaled coefficients
__global__ __launch_bounds__(64) void k_scalars(const float* __restrict__ adaptive_tau,
                          const float* __restrict__ eta_p,
                          const float* __restrict__ tau_sys_p,
                          const float* __restrict__ lls_p,
                          float* __restrict__ ws, float* __restrict__ out)
{
    int b = blockIdx.x, r = threadIdx.x;
    float ev  = ws[WS_EVEC + b * 64 + r];
    float gv  = ws[WS_G + b * 64 + r];
    float gtv = ws[WS_GT + b * 64 + r];
    float s1 = wave_reduce_sum(gv * ev);      // <U, h x eV>
    float s2 = wave_reduce_sum(gtv * ev);     // <Ut, h x eV>
    float s3 = wave_reduce_sum(ev * ev);      // |eV|^2
    if (r == 0) {
        float xm  = ws[WS_XMAG + b];
        float rel = sqrtf(ws[WS_ERRSQ + b]) / (xm + 1e-6f);
        float ent = 0.5f * logf(17.07946844534713f * (ws[WS_EVMEAN + b] + 1e-6f));
        ent = fminf(fmaxf(ent, 0.f), 2.f);
        float nat = fminf(0.999f * adaptive_tau[b] + 0.001f * rel, 0.8f);
        out[OUT_AT + b] = nat;
        float ctau = 0.5f * (1.f + 0.1f * ent);
        float etau = 0.3f * ctau + 0.7f * nat;
        float s = 1.f / (1.f + expf(-(rel - etau) * 10.f));
        out[OUT_SUR + b] = s;
        ws[WS_SUR + b] = s;
        float tsys = tau_sys_p[0];
        float tsc  = fmaxf(tsys, 0.01f);
        float tdyn = tsc / (1.f + s * expf(lls_p[0]));
        float teff = fminf(fmaxf(tdyn, 0.01f), 50.f);
        float dt   = fminf(fmaxf(0.1f / (teff + 0.1f), 0.01f), 0.5f);
        float u = 1.f / (1.f + expf(-(tsys - 0.01f) * 100.f));
        ws[WS_COEF_A + b] = u * (1.f - dt) + (1.f - u) * 0.05f;
        ws[WS_COEF_B + b] = u * dt + (1.f - u) * 0.95f;
        float lam = 0.01f * (1.f + s);
        float a  = 1.f - 0.1f * lam;
        float tc = 0.1f * lam;
        float ch = 0.1f * eta_p[0] * s;
        float fro2 = a * a * ws[WS_SU + b] + tc * tc * ws[WS_ST + b]
                   + 2.f * a * tc * ws[WS_SUT + b]
                   + 2.f * a * ch * s1 + 2.f * tc * ch * s2
                   + ch * ch * ws[WS_SH2 + b] * s3;
        float scale = fminf(1.0f / (sqrtf(fro2) + 1e-6f), 1.5f);
        ws[WS_CUS + b] = a * scale;
        ws[WS_CTS + b] = tc * scale;
        ws[WS_CHS + b] = ch * scale;
    }
}

// h_new with coalesced errT/xnT reads
__global__ __launch_bounds__(256) void k_hnew(const float* __restrict__ W,
    const float* __restrict__ Bm, float* __restrict__ ws, float* __restrict__ out)
{
    int b = threadIdx.x & 63, ig = threadIdx.x >> 6;
    int hh = blockIdx.x * 8 + ig * 2;
    const float4* eT = (const float4*)(ws + WS_ERRT);
    const float4* xT = (const float4*)(ws + WS_XNT);
    const float4* w0 = (const float4*)(W + hh * II);
    const float4* w1 = w0 + 128;
    const float4* m0 = (const float4*)(Bm + hh * II);
    const float4* m1 = m0 + 128;
    float aw0 = 0, aw1 = 0, ab0 = 0, ab1 = 0;
    #pragma unroll 4
    for (int t = 0; t < 128; ++t) {
        float4 e  = eT[t * 64 + b];
        float4 xn = xT[t * 64 + b];
        float4 v0 = w0[t], v1 = w1[t], u0 = m0[t], u1 = m1[t];
        aw0 += dot4(e, v0);
        aw1 += dot4(e, v1);
        ab0 += dot4(xn, u0);
        ab1 += dot4(xn, u1);
    }
    float s = ws[WS_SUR + b];
    float A = ws[WS_COEF_A + b], Bc = ws[WS_COEF_B + b];
    float4 hv = ((const float4*)(ws + WS_HT))[(hh >> 2) * 64 + b];
    float h0 = (hh & 2) ? hv.z : hv.x;
    float h1 = (hh & 2) ? hv.w : hv.y;
    float ht0 = tanhf(0.7f * h0 + 0.2f * ab0 + 0.3f * s * aw0);
    float ht1 = tanhf(0.7f * h1 + 0.2f * ab1 + 0.3f * s * aw1);
    out[OUT_HNEW + b * HH + hh]     = A * h0 + Bc * ht0;
    out[OUT_HNEW + b * HH + hh + 1] = A * h1 + Bc * ht1;
}

// Single scaled streaming U pass: no reductions, no atomics, no barriers.
// 512 blocks x 256 threads x 16 float4 = 2,097,152 float4 = exactly U.
__global__ __launch_bounds__(256) void k_upd(const float* __restrict__ U,
    const float* __restrict__ Ut, const float* __restrict__ h,
    const float* __restrict__ ws, float* __restrict__ uout)
{
    int b = blockIdx.x >> 3;                       // 8 blocks per batch
    int j0 = blockIdx.x * 4096 + threadIdx.x;      // float4 index
    int r = (j0 << 2) & 63;                        // constant across strides of 256
    float4 ev4 = *(const float4*)(ws + WS_EVEC + b * RR + r);
    float as = ws[WS_CUS + b];
    float ts = ws[WS_CTS + b];
    float cs = ws[WS_CHS + b];
    const float*  hb = h + b * HH;
    const float4* U4 = (const float4*)U;
    const float4* T4 = (const float4*)Ut;
    float4* O4 = (float4*)uout;
    #pragma unroll
    for (int kk = 0; kk < 4; ++kk) {
        float4 u[4], tt[4];
        int jj[4];
        #pragma unroll
        for (int q = 0; q < 4; ++q) {
            jj[q] = j0 + (kk * 4 + q) * 256;
            u[q]  = U4[jj[q]];
            tt[q] = T4[jj[q]];
        }
        #pragma unroll
        for (int q = 0; q < 4; ++q) {
            int e = (jj[q] << 2) & 131071;         // element offset within batch
            float c = cs * hb[e >> 6];
            float4 o;
            o.x = as * u[q].x + ts * tt[q].x + c * ev4.x;
            o.y = as * u[q].y + ts * tt[q].y + c * ev4.y;
            o.z = as * u[q].z + ts * tt[q].z + c * ev4.z;
            o.w = as * u[q].w + ts * tt[q].w + c * ev4.w;
            O4[jj[q]] = o;
        }
    }
}

extern "C" void kernel_launch(void* const* d_in, const int* in_sizes, int n_in,
                              void* d_out, int out_size, void* d_ws, size_t ws_size,
                              hipStream_t stream) {
    const float* x   = (const float*)d_in[0];
    const float* h   = (const float*)d_in[1];
    const float* U   = (const float*)d_in[2];
    const float* Ut  = (const float*)d_in[3];
    const float* em  = (const float*)d_in[4];
    const float* ev  = (const float*)d_in[5];
    const float* at  = (const float*)d_in[6];
    const float* C   = (const float*)d_in[7];
    const float* W   = (const float*)d_in[8];
    const float* Bm  = (const float*)d_in[9];
    const float* V   = (const float*)d_in[10];
    const float* eta = (const float*)d_in[11];
    const float* tau = (const float*)d_in[12];
    const float* lls = (const float*)d_in[13];
    float* out = (float*)d_out;
    float* ws  = (float*)d_ws;

    // zero accumulators (Su..Sh2, g, gt) + pred in one contiguous memset
    hipMemsetAsync(ws + WS_SU, 0, (WS_ERRT - WS_SU) * sizeof(float), stream);

    k_ht     <<<64,   256, 0, stream>>>(h, ws);
    k_fro    <<<512,  256, 0, stream>>>(U, Ut, h, ws);
    k_pred   <<<256,  256, 0, stream>>>(ws + WS_HT, C, ws + WS_PRED);
    k_combine<<<64,   128, 0, stream>>>(x, em, ev, V, ws, out);
    k_scalars<<<64,   64,  0, stream>>>(at, eta, tau, lls, ws, out);
    k_hnew   <<<256,  256, 0, stream>>>(W, Bm, ws, out);
    k_upd    <<<512,  256, 0, stream>>>(U, Ut, h, ws, out + OUT_U);
}